// Round 7
// baseline (545.386 us; speedup 1.0000x reference)
//
#include <hip/hip_runtime.h>

// GraphPolicyNetwork: 2-layer GraphSAGE (rank-1 weights -> scalar edge passes)
// + dense head [64x4096]@[4096x4096]. All tensors fp32 (proven round 4).
//
// R6 post-mortem: gemm_x was 131 us at VALUBusy 10.5% -- a 1-deep dependent
// load pipeline (load -> vmcnt(0) -> 64 FMA) at 1 wave/SIMD. Duty model
// 128/(128+900) = 12% matched. Fix: manually rotated double-buffered
// register prefetch (2 batches of 8 w3 values; compile-time buffer indices
// so no scratch), keeping 8 loads in flight under the FMA stream.
// Edge passes: per-XCD replica accumulators (workgroup-scope atomics in the
// local L2, replica = HW_REG_XCC_ID), proven in R6 (edge_pass1 206 -> off
// the top-5). Fast path needs 20 MB of d_ws; falls back to the proven R4
// device-atomic pipeline if smaller.

#define NTOT (64 * 4096)      // 262144 total nodes
#define NHID 128
#define GK   4096             // GEMM K == N_NODES
#define KCH  256              // K per chunk
#define KCHUNKS 16
#define NXCD 8
#define MASK44 ((1ULL << 44) - 1)

typedef unsigned long long u64;

__device__ __forceinline__ int xcc_id() {
    // s_getreg_b32 hwreg(HW_REG_XCC_ID=20, offset 0, size 32): simm16 = 63508.
    return (int)(__builtin_amdgcn_s_getreg(63508) & 7u);
}

__device__ __forceinline__ float fast_tanh(float x) {
    float ax = fabsf(x);
    float t  = __expf(-2.0f * ax);
    float r  = (1.0f - t) / (1.0f + t);
    return copysignf(r, x);
}

// ======================= FAST PATH (ws >= 20 MB) ==========================

// ---- edge pass 1: packed (deg | fixed-point sum) into per-XCD replica ----
__global__ void edge_pass1_x(const int* __restrict__ src, const int* __restrict__ dst,
                             const float* __restrict__ nf, u64* __restrict__ rep,
                             int n_edges) {
    u64* myrep = rep + (size_t)xcc_id() * NTOT;
    int e = blockIdx.x * blockDim.x + threadIdx.x;
    if (e >= n_edges) return;
    float v = nf[src[e]];
    // (v+8) in (2,14); field = (v+8)*2^32; per-replica sum < 64*14*2^32 < 2^42.
    u64 enc = (1ULL << 44) +
              (u64)(long long)llrintf(fmaf(v, 4294967296.0f, 8.0f * 4294967296.0f));
    __hip_atomic_fetch_add(&myrep[dst[e]], enc, __ATOMIC_RELAXED,
                           __HIP_MEMORY_SCOPE_WORKGROUP);
}

// ---- node pass 1: decode replicas; selfpart, sp, deg out ----
__global__ void node1_x(const float* __restrict__ nf, const u64* __restrict__ rep,
                        const float* __restrict__ w_s1, const float* __restrict__ w_n1,
                        const float* __restrict__ bb1,
                        const float* __restrict__ w_s2, const float* __restrict__ w_n2,
                        float* __restrict__ degf, float* __restrict__ selfp,
                        float* __restrict__ sp) {
    __shared__ float lws1[NHID], lwn1[NHID], lb1[NHID], lws2[NHID], lwn2[NHID];
    int tid = threadIdx.x;
    if (tid < NHID) {
        lws1[tid] = w_s1[tid];
        lwn1[tid] = w_n1[tid];
        lb1[tid]  = bb1[tid];
        lws2[tid] = w_s2[tid];
        lwn2[tid] = w_n2[tid];
    }
    __syncthreads();
    int v = blockIdx.x * blockDim.x + tid;
    int degi = 0;
    double sfix = 0.0;
#pragma unroll
    for (int r = 0; r < NXCD; ++r) {
        u64 x = rep[(size_t)r * NTOT + v];
        degi += (int)(x >> 44);
        sfix += (double)(x & MASK44);
    }
    float hsum = (float)(sfix * (1.0 / 4294967296.0) - 8.0 * (double)degi);
    float hn = hsum / fmaxf((float)degi, 1.0f);
    float f = nf[v];
    float a = 0.0f, s = 0.0f;
#pragma unroll 8
    for (int j = 0; j < NHID; ++j) {
        float t = fast_tanh(fmaf(f, lws1[j], fmaf(hn, lwn1[j], lb1[j])));
        a = fmaf(t, lws2[j], a);
        s = fmaf(t, lwn2[j], s);
    }
    degf[v]  = (float)degi;
    selfp[v] = a;
    sp[v]    = s;
}

// ---- edge pass 2: fp32 per-XCD replica accumulation ----
__global__ void edge_pass2_x(const int* __restrict__ src, const int* __restrict__ dst,
                             const float* __restrict__ sp, float* __restrict__ rep2,
                             int n_edges) {
    float* myrep = rep2 + (size_t)xcc_id() * NTOT;
    int e = blockIdx.x * blockDim.x + threadIdx.x;
    if (e >= n_edges) return;
    __hip_atomic_fetch_add(&myrep[dst[e]], sp[src[e]], __ATOMIC_RELAXED,
                           __HIP_MEMORY_SCOPE_WORKGROUP);
}

// ---- node pass 2: out1 (fp32); h2t K-major ----
__global__ void node2_x(const float* __restrict__ selfp, const float* __restrict__ rep2,
                        const float* __restrict__ degf, const float* __restrict__ b2p,
                        float* __restrict__ out1, float* __restrict__ h2t) {
    int v = blockIdx.x * blockDim.x + threadIdx.x;
    float agg2 = 0.0f;
#pragma unroll
    for (int r = 0; r < NXCD; ++r) agg2 += rep2[(size_t)r * NTOT + v];
    float o = selfp[v] + agg2 / fmaxf(degf[v], 1.0f) + b2p[0];
    out1[v] = o;
    int r = v >> 12;     // graph (row) index 0..63
    int k = v & 4095;    // node-in-graph (K) index
    h2t[k * 64 + r] = fast_tanh(o);
}

// ---- GEMM: Cpart[kc][r][n] = sum_{k in chunk} h2t[k][r] * w3[k][n] ----
// One thread per column n, 64 row accumulators (h2 values wave-uniform ->
// s_loads). w3 loads manually rotated: two 8-deep register batches so 8
// loads stay in flight while the previous batch's 512 FMAs execute.
__global__ void __launch_bounds__(256) gemm_x(const float* __restrict__ h2t,
                                              const float* __restrict__ w3,
                                              float* __restrict__ Cpart) {
    int n  = blockIdx.x * 256 + threadIdx.x;
    int k0 = blockIdx.y * KCH;
    float acc[64];
#pragma unroll
    for (int r = 0; r < 64; ++r) acc[r] = 0.0f;

    const float* wp = w3 + (size_t)k0 * GK + n;   // column n, row k0
    float bvA[8], bvB[8];

    // prologue: batch A <- k0..k0+7
#pragma unroll
    for (int j = 0; j < 8; ++j) bvA[j] = wp[(size_t)j * GK];

    // steady state: 16 k's per iteration, rotate A/B at compile time
    for (int kk = 0; kk < KCH; kk += 16) {
        // issue B <- kk+8..kk+15 while consuming A
#pragma unroll
        for (int j = 0; j < 8; ++j) bvB[j] = wp[(size_t)(kk + 8 + j) * GK];
        {
            const float* Ab = h2t + (k0 + kk) * 64;
#pragma unroll
            for (int j = 0; j < 8; ++j) {
                const float* Ak = Ab + j * 64;
                float b = bvA[j];
#pragma unroll
                for (int r = 0; r < 64; ++r) acc[r] = fmaf(Ak[r], b, acc[r]);
            }
        }
        // issue A <- kk+16..kk+23 (guarded, uniform) while consuming B
        if (kk + 16 < KCH) {
#pragma unroll
            for (int j = 0; j < 8; ++j) bvA[j] = wp[(size_t)(kk + 16 + j) * GK];
        }
        {
            const float* Ab = h2t + (k0 + kk + 8) * 64;
#pragma unroll
            for (int j = 0; j < 8; ++j) {
                const float* Ak = Ab + j * 64;
                float b = bvB[j];
#pragma unroll
                for (int r = 0; r < 64; ++r) acc[r] = fmaf(Ak[r], b, acc[r]);
            }
        }
    }

    float* Cp = Cpart + (size_t)blockIdx.y * NTOT;
#pragma unroll
    for (int r = 0; r < 64; ++r) Cp[r * GK + n] = acc[r];
}

// ---- reduce K-chunk partials + b3 -> out2 ----
__global__ void reduce_x(const float* __restrict__ Cpart, const float* __restrict__ b3,
                         float* __restrict__ out2) {
    int v = blockIdx.x * blockDim.x + threadIdx.x;
    float s = b3[v & 4095];
#pragma unroll
    for (int kc = 0; kc < KCHUNKS; ++kc) s += Cpart[(size_t)kc * NTOT + v];
    out2[v] = s;
}

// ================== FALLBACK PATH (proven R4 pipeline) ====================

__global__ void edge_pass1_f(const int* __restrict__ src, const int* __restrict__ dst,
                             const float* __restrict__ nf, float* __restrict__ agg,
                             float* __restrict__ deg, int n_edges) {
    int e = blockIdx.x * blockDim.x + threadIdx.x;
    if (e >= n_edges) return;
    int s = src[e], d = dst[e];
    atomicAdd(&agg[d], nf[s]);
    atomicAdd(&deg[d], 1.0f);
}

__global__ void node1_f(const float* __restrict__ nf, float* s0,
                        const float* __restrict__ deg,
                        const float* __restrict__ w_s1, const float* __restrict__ w_n1,
                        const float* __restrict__ bb1,
                        const float* __restrict__ w_s2, const float* __restrict__ w_n2,
                        float* __restrict__ sp) {
    __shared__ float lws1[NHID], lwn1[NHID], lb1[NHID], lws2[NHID], lwn2[NHID];
    int tid = threadIdx.x;
    if (tid < NHID) {
        lws1[tid] = w_s1[tid];
        lwn1[tid] = w_n1[tid];
        lb1[tid]  = bb1[tid];
        lws2[tid] = w_s2[tid];
        lwn2[tid] = w_n2[tid];
    }
    __syncthreads();
    int v = blockIdx.x * blockDim.x + tid;
    float f  = nf[v];
    float hn = s0[v] / fmaxf(deg[v], 1.0f);
    float a = 0.0f, s = 0.0f;
#pragma unroll 8
    for (int j = 0; j < NHID; ++j) {
        float t = fast_tanh(fmaf(f, lws1[j], fmaf(hn, lwn1[j], lb1[j])));
        a = fmaf(t, lws2[j], a);
        s = fmaf(t, lwn2[j], s);
    }
    s0[v] = a;
    sp[v] = s;
}

__global__ void edge_pass2_f(const int* __restrict__ src, const int* __restrict__ dst,
                             const float* __restrict__ sp, float* __restrict__ agg2,
                             int n_edges) {
    int e = blockIdx.x * blockDim.x + threadIdx.x;
    if (e >= n_edges) return;
    atomicAdd(&agg2[dst[e]], sp[src[e]]);
}

__global__ void node2_f(const float* __restrict__ s0, const float* __restrict__ agg2,
                        const float* __restrict__ deg, const float* __restrict__ b2p,
                        const float* __restrict__ b3p,
                        float* __restrict__ out1, float* __restrict__ h2t,
                        float* __restrict__ out2) {
    int v = blockIdx.x * blockDim.x + threadIdx.x;
    float o = s0[v] + agg2[v] / fmaxf(deg[v], 1.0f) + b2p[0];
    out1[v] = o;
    int r = v >> 12;
    int k = v & 4095;
    h2t[k * 64 + r] = fast_tanh(o);
    out2[v] = b3p[v & 4095];
}

__global__ void __launch_bounds__(256) gemm_f(const float* __restrict__ h2t,
                                              const float* __restrict__ w3,
                                              float* __restrict__ out2) {
    int n  = blockIdx.x * 256 + threadIdx.x;
    int k0 = blockIdx.y * KCH;
    float acc[64];
#pragma unroll
    for (int r = 0; r < 64; ++r) acc[r] = 0.0f;
    for (int k = k0; k < k0 + KCH; ++k) {
        float bv = w3[(size_t)k * GK + n];
        const float* Ak = h2t + k * 64;
#pragma unroll
        for (int r = 0; r < 64; ++r) acc[r] = fmaf(Ak[r], bv, acc[r]);
    }
#pragma unroll
    for (int r = 0; r < 64; ++r) atomicAdd(&out2[r * GK + n], acc[r]);
}

// ==========================================================================

extern "C" void kernel_launch(void* const* d_in, const int* in_sizes, int n_in,
                              void* d_out, int out_size, void* d_ws, size_t ws_size,
                              hipStream_t stream) {
    const float* nf  = (const float*)d_in[0];
    const int*   src = (const int*)d_in[1];
    const int*   dst = (const int*)d_in[2];
    const float* ws1 = (const float*)d_in[3];
    const float* wn1 = (const float*)d_in[4];
    const float* b1  = (const float*)d_in[5];
    const float* ws2 = (const float*)d_in[6];
    const float* wn2 = (const float*)d_in[7];
    const float* b2  = (const float*)d_in[8];
    const float* w3  = (const float*)d_in[9];
    const float* b3  = (const float*)d_in[10];
    float* out1 = (float*)d_out;
    float* out2 = (float*)d_out + NTOT;

    int n_edges = in_sizes[1];
    int eb = (n_edges + 255) / 256;

    if (ws_size >= (size_t)20 * 1024 * 1024) {
        // -------- fast path: 20 MB layout --------
        char* base = (char*)d_ws;
        u64*   rep   = (u64*)base;                               // 16 MB
        float* degf  = (float*)(base + (((size_t)16) << 20));    // 1 MB
        float* selfp = (float*)(base + (((size_t)17) << 20));    // 1 MB
        float* sp    = (float*)(base + (((size_t)18) << 20));    // 1 MB
        float* h2t   = (float*)(base + (((size_t)19) << 20));    // 1 MB
        float* rep2  = (float*)base;   // 8 MB, reuses rep after node1
        float* Cpart = (float*)base;   // 16 MB, reuses rep after node2

        (void)hipMemsetAsync(rep, 0, (size_t)NXCD * NTOT * sizeof(u64), stream);
        edge_pass1_x<<<eb, 256, 0, stream>>>(src, dst, nf, rep, n_edges);
        node1_x<<<NTOT / 256, 256, 0, stream>>>(nf, rep, ws1, wn1, b1, ws2, wn2,
                                                degf, selfp, sp);
        (void)hipMemsetAsync(rep2, 0, (size_t)NXCD * NTOT * sizeof(float), stream);
        edge_pass2_x<<<eb, 256, 0, stream>>>(src, dst, sp, rep2, n_edges);
        node2_x<<<NTOT / 256, 256, 0, stream>>>(selfp, rep2, degf, b2, out1, h2t);
        gemm_x<<<dim3(GK / 256, KCHUNKS), 256, 0, stream>>>(h2t, w3, Cpart);
        reduce_x<<<NTOT / 256, 256, 0, stream>>>(Cpart, b3, out2);
    } else {
        // -------- fallback: proven R4 pipeline (4.19 MB) --------
        float* ws = (float*)d_ws;
        float* S0 = ws;            // agg -> selfpart
        float* S1 = ws + 1 * NTOT; // deg
        float* S2 = ws + 2 * NTOT; // agg2
        float* S3 = ws + 3 * NTOT; // sp -> h2t

        (void)hipMemsetAsync(S0, 0, (size_t)3 * NTOT * sizeof(float), stream);
        edge_pass1_f<<<eb, 256, 0, stream>>>(src, dst, nf, S0, S1, n_edges);
        node1_f<<<NTOT / 256, 256, 0, stream>>>(nf, S0, S1, ws1, wn1, b1, ws2, wn2, S3);
        edge_pass2_f<<<eb, 256, 0, stream>>>(src, dst, S3, S2, n_edges);
        node2_f<<<NTOT / 256, 256, 0, stream>>>(S0, S2, S1, b2, b3, out1, S3, out2);
        gemm_f<<<dim3(GK / 256, KCHUNKS), 256, 0, stream>>>(S3, w3, out2);
    }
}

// Round 8
// 487.542 us; speedup vs baseline: 1.1186x; 1.1186x over previous
//
#include <hip/hip_runtime.h>

// GraphPolicyNetwork: 2-layer GraphSAGE (rank-1 weights -> scalar edge passes)
// + dense head [64x4096]@[4096x4096]. All tensors fp32 (proven round 4).
//
// R7 post-mortem: acc[64]/thread forced the compiler to park accumulators
// in AGPRs (VGPR_Count 36/64 < 64 needed) and shuttle v_accvgpr_read/write
// around every FMA -- VALU work tripled; 256-block grid gave 1 wave/SIMD so
// nothing hid the ~900-cyc w3 load latency. Fix: 64x64 block tile, 4 waves
// x (16 rows x 64 cols) -> acc[16]/thread (~45 VGPR, no AGPR traffic),
// grid 64x16 = 1024 blocks = 4 waves/SIMD, 8-deep double-buffered w3
// prefetch. Edge passes: per-XCD replica accumulators (workgroup-scope
// atomics in the local L2, replica = HW_REG_XCC_ID), proven R6.
// Fast path needs 20 MB d_ws; falls back to proven R4 pipeline if smaller.

#define NTOT (64 * 4096)      // 262144 total nodes
#define NHID 128
#define GK   4096             // GEMM K == N_NODES
#define KCH  256              // K per chunk
#define KCHUNKS 16
#define NXCD 8
#define MASK44 ((1ULL << 44) - 1)

typedef unsigned long long u64;

__device__ __forceinline__ int xcc_id() {
    // s_getreg_b32 hwreg(HW_REG_XCC_ID=20, offset 0, size 32): simm16 = 63508.
    return (int)(__builtin_amdgcn_s_getreg(63508) & 7u);
}

__device__ __forceinline__ float fast_tanh(float x) {
    float ax = fabsf(x);
    float t  = __expf(-2.0f * ax);
    float r  = (1.0f - t) / (1.0f + t);
    return copysignf(r, x);
}

// ======================= FAST PATH (ws >= 20 MB) ==========================

// ---- edge pass 1: packed (deg | fixed-point sum) into per-XCD replica ----
__global__ void edge_pass1_x(const int* __restrict__ src, const int* __restrict__ dst,
                             const float* __restrict__ nf, u64* __restrict__ rep,
                             int n_edges) {
    u64* myrep = rep + (size_t)xcc_id() * NTOT;
    int e = blockIdx.x * blockDim.x + threadIdx.x;
    if (e >= n_edges) return;
    float v = nf[src[e]];
    // (v+8) in (2,14); field = (v+8)*2^32; per-replica sum < 64*14*2^32 < 2^42.
    u64 enc = (1ULL << 44) +
              (u64)(long long)llrintf(fmaf(v, 4294967296.0f, 8.0f * 4294967296.0f));
    __hip_atomic_fetch_add(&myrep[dst[e]], enc, __ATOMIC_RELAXED,
                           __HIP_MEMORY_SCOPE_WORKGROUP);
}

// ---- node pass 1: decode replicas; selfpart, sp, deg out ----
__global__ void node1_x(const float* __restrict__ nf, const u64* __restrict__ rep,
                        const float* __restrict__ w_s1, const float* __restrict__ w_n1,
                        const float* __restrict__ bb1,
                        const float* __restrict__ w_s2, const float* __restrict__ w_n2,
                        float* __restrict__ degf, float* __restrict__ selfp,
                        float* __restrict__ sp) {
    __shared__ float lws1[NHID], lwn1[NHID], lb1[NHID], lws2[NHID], lwn2[NHID];
    int tid = threadIdx.x;
    if (tid < NHID) {
        lws1[tid] = w_s1[tid];
        lwn1[tid] = w_n1[tid];
        lb1[tid]  = bb1[tid];
        lws2[tid] = w_s2[tid];
        lwn2[tid] = w_n2[tid];
    }
    __syncthreads();
    int v = blockIdx.x * blockDim.x + tid;
    int degi = 0;
    double sfix = 0.0;
#pragma unroll
    for (int r = 0; r < NXCD; ++r) {
        u64 x = rep[(size_t)r * NTOT + v];
        degi += (int)(x >> 44);
        sfix += (double)(x & MASK44);
    }
    float hsum = (float)(sfix * (1.0 / 4294967296.0) - 8.0 * (double)degi);
    float hn = hsum / fmaxf((float)degi, 1.0f);
    float f = nf[v];
    float a = 0.0f, s = 0.0f;
#pragma unroll 8
    for (int j = 0; j < NHID; ++j) {
        float t = fast_tanh(fmaf(f, lws1[j], fmaf(hn, lwn1[j], lb1[j])));
        a = fmaf(t, lws2[j], a);
        s = fmaf(t, lwn2[j], s);
    }
    degf[v]  = (float)degi;
    selfp[v] = a;
    sp[v]    = s;
}

// ---- edge pass 2: fp32 per-XCD replica accumulation ----
__global__ void edge_pass2_x(const int* __restrict__ src, const int* __restrict__ dst,
                             const float* __restrict__ sp, float* __restrict__ rep2,
                             int n_edges) {
    float* myrep = rep2 + (size_t)xcc_id() * NTOT;
    int e = blockIdx.x * blockDim.x + threadIdx.x;
    if (e >= n_edges) return;
    __hip_atomic_fetch_add(&myrep[dst[e]], sp[src[e]], __ATOMIC_RELAXED,
                           __HIP_MEMORY_SCOPE_WORKGROUP);
}

// ---- node pass 2: out1 (fp32); h2t K-major ----
__global__ void node2_x(const float* __restrict__ selfp, const float* __restrict__ rep2,
                        const float* __restrict__ degf, const float* __restrict__ b2p,
                        float* __restrict__ out1, float* __restrict__ h2t) {
    int v = blockIdx.x * blockDim.x + threadIdx.x;
    float agg2 = 0.0f;
#pragma unroll
    for (int r = 0; r < NXCD; ++r) agg2 += rep2[(size_t)r * NTOT + v];
    float o = selfp[v] + agg2 / fmaxf(degf[v], 1.0f) + b2p[0];
    out1[v] = o;
    int r = v >> 12;     // graph (row) index 0..63
    int k = v & 4095;    // node-in-graph (K) index
    h2t[k * 64 + r] = fast_tanh(o);
}

// ---- GEMM: Cpart[kc][rows][cols] ; block tile 64 rows x 64 cols ----
// 4 waves/block, wave w: rows [16w,16w+16) x all 64 cols; lane = col.
// acc[16]/thread (~45 VGPR: no AGPR shuttling). Grid 64 x 16 = 1024 blocks
// = 4 waves/SIMD. 8-deep double-buffered w3 prefetch hides load latency.
__global__ void __launch_bounds__(256) gemm_x(const float* __restrict__ h2t,
                                              const float* __restrict__ w3,
                                              float* __restrict__ Cpart) {
    int lane = threadIdx.x & 63;
    int wv   = threadIdx.x >> 6;          // wave 0..3
    int col  = blockIdx.x * 64 + lane;    // 64 col-blocks
    int k0   = blockIdx.y * KCH;
    int row0 = wv * 16;

    float acc[16];
#pragma unroll
    for (int r = 0; r < 16; ++r) acc[r] = 0.0f;

    const float* wp = w3 + (size_t)k0 * GK + col;
    float bvA[8], bvB[8];

    // prologue: batch A <- k0..k0+7
#pragma unroll
    for (int j = 0; j < 8; ++j) bvA[j] = wp[(size_t)j * GK];

    for (int kk = 0; kk < KCH; kk += 16) {
        // issue B <- kk+8..kk+15 while consuming A
#pragma unroll
        for (int j = 0; j < 8; ++j) bvB[j] = wp[(size_t)(kk + 8 + j) * GK];
#pragma unroll
        for (int j = 0; j < 8; ++j) {
            const float* Ah = h2t + (k0 + kk + j) * 64 + row0;  // wave-uniform
            float b = bvA[j];
#pragma unroll
            for (int r = 0; r < 16; ++r) acc[r] = fmaf(Ah[r], b, acc[r]);
        }
        // issue A <- kk+16..kk+23 while consuming B
        if (kk + 16 < KCH) {
#pragma unroll
            for (int j = 0; j < 8; ++j) bvA[j] = wp[(size_t)(kk + 16 + j) * GK];
        }
#pragma unroll
        for (int j = 0; j < 8; ++j) {
            const float* Ah = h2t + (k0 + kk + 8 + j) * 64 + row0;
            float b = bvB[j];
#pragma unroll
            for (int r = 0; r < 16; ++r) acc[r] = fmaf(Ah[r], b, acc[r]);
        }
    }

    float* Cp = Cpart + (size_t)blockIdx.y * NTOT + (size_t)row0 * GK + col;
#pragma unroll
    for (int r = 0; r < 16; ++r) Cp[(size_t)r * GK] = acc[r];
}

// ---- reduce K-chunk partials + b3 -> out2 ----
__global__ void reduce_x(const float* __restrict__ Cpart, const float* __restrict__ b3,
                         float* __restrict__ out2) {
    int v = blockIdx.x * blockDim.x + threadIdx.x;
    float s = b3[v & 4095];
#pragma unroll
    for (int kc = 0; kc < KCHUNKS; ++kc) s += Cpart[(size_t)kc * NTOT + v];
    out2[v] = s;
}

// ================== FALLBACK PATH (proven R4 pipeline) ====================

__global__ void edge_pass1_f(const int* __restrict__ src, const int* __restrict__ dst,
                             const float* __restrict__ nf, float* __restrict__ agg,
                             float* __restrict__ deg, int n_edges) {
    int e = blockIdx.x * blockDim.x + threadIdx.x;
    if (e >= n_edges) return;
    int s = src[e], d = dst[e];
    atomicAdd(&agg[d], nf[s]);
    atomicAdd(&deg[d], 1.0f);
}

__global__ void node1_f(const float* __restrict__ nf, float* s0,
                        const float* __restrict__ deg,
                        const float* __restrict__ w_s1, const float* __restrict__ w_n1,
                        const float* __restrict__ bb1,
                        const float* __restrict__ w_s2, const float* __restrict__ w_n2,
                        float* __restrict__ sp) {
    __shared__ float lws1[NHID], lwn1[NHID], lb1[NHID], lws2[NHID], lwn2[NHID];
    int tid = threadIdx.x;
    if (tid < NHID) {
        lws1[tid] = w_s1[tid];
        lwn1[tid] = w_n1[tid];
        lb1[tid]  = bb1[tid];
        lws2[tid] = w_s2[tid];
        lwn2[tid] = w_n2[tid];
    }
    __syncthreads();
    int v = blockIdx.x * blockDim.x + tid;
    float f  = nf[v];
    float hn = s0[v] / fmaxf(deg[v], 1.0f);
    float a = 0.0f, s = 0.0f;
#pragma unroll 8
    for (int j = 0; j < NHID; ++j) {
        float t = fast_tanh(fmaf(f, lws1[j], fmaf(hn, lwn1[j], lb1[j])));
        a = fmaf(t, lws2[j], a);
        s = fmaf(t, lwn2[j], s);
    }
    s0[v] = a;
    sp[v] = s;
}

__global__ void edge_pass2_f(const int* __restrict__ src, const int* __restrict__ dst,
                             const float* __restrict__ sp, float* __restrict__ agg2,
                             int n_edges) {
    int e = blockIdx.x * blockDim.x + threadIdx.x;
    if (e >= n_edges) return;
    atomicAdd(&agg2[dst[e]], sp[src[e]]);
}

__global__ void node2_f(const float* __restrict__ s0, const float* __restrict__ agg2,
                        const float* __restrict__ deg, const float* __restrict__ b2p,
                        const float* __restrict__ b3p,
                        float* __restrict__ out1, float* __restrict__ h2t,
                        float* __restrict__ out2) {
    int v = blockIdx.x * blockDim.x + threadIdx.x;
    float o = s0[v] + agg2[v] / fmaxf(deg[v], 1.0f) + b2p[0];
    out1[v] = o;
    int r = v >> 12;
    int k = v & 4095;
    h2t[k * 64 + r] = fast_tanh(o);
    out2[v] = b3p[v & 4095];
}

__global__ void __launch_bounds__(256) gemm_f(const float* __restrict__ h2t,
                                              const float* __restrict__ w3,
                                              float* __restrict__ out2) {
    int n  = blockIdx.x * 256 + threadIdx.x;
    int k0 = blockIdx.y * KCH;
    float acc[64];
#pragma unroll
    for (int r = 0; r < 64; ++r) acc[r] = 0.0f;
    for (int k = k0; k < k0 + KCH; ++k) {
        float bv = w3[(size_t)k * GK + n];
        const float* Ak = h2t + k * 64;
#pragma unroll
        for (int r = 0; r < 64; ++r) acc[r] = fmaf(Ak[r], bv, acc[r]);
    }
#pragma unroll
    for (int r = 0; r < 64; ++r) atomicAdd(&out2[r * GK + n], acc[r]);
}

// ==========================================================================

extern "C" void kernel_launch(void* const* d_in, const int* in_sizes, int n_in,
                              void* d_out, int out_size, void* d_ws, size_t ws_size,
                              hipStream_t stream) {
    const float* nf  = (const float*)d_in[0];
    const int*   src = (const int*)d_in[1];
    const int*   dst = (const int*)d_in[2];
    const float* ws1 = (const float*)d_in[3];
    const float* wn1 = (const float*)d_in[4];
    const float* b1  = (const float*)d_in[5];
    const float* ws2 = (const float*)d_in[6];
    const float* wn2 = (const float*)d_in[7];
    const float* b2  = (const float*)d_in[8];
    const float* w3  = (const float*)d_in[9];
    const float* b3  = (const float*)d_in[10];
    float* out1 = (float*)d_out;
    float* out2 = (float*)d_out + NTOT;

    int n_edges = in_sizes[1];
    int eb = (n_edges + 255) / 256;

    if (ws_size >= (size_t)20 * 1024 * 1024) {
        // -------- fast path: 20 MB layout --------
        char* base = (char*)d_ws;
        u64*   rep   = (u64*)base;                               // 16 MB
        float* degf  = (float*)(base + (((size_t)16) << 20));    // 1 MB
        float* selfp = (float*)(base + (((size_t)17) << 20));    // 1 MB
        float* sp    = (float*)(base + (((size_t)18) << 20));    // 1 MB
        float* h2t   = (float*)(base + (((size_t)19) << 20));    // 1 MB
        float* rep2  = (float*)base;   // 8 MB, reuses rep after node1
        float* Cpart = (float*)base;   // 16 MB, reuses rep after node2

        (void)hipMemsetAsync(rep, 0, (size_t)NXCD * NTOT * sizeof(u64), stream);
        edge_pass1_x<<<eb, 256, 0, stream>>>(src, dst, nf, rep, n_edges);
        node1_x<<<NTOT / 256, 256, 0, stream>>>(nf, rep, ws1, wn1, b1, ws2, wn2,
                                                degf, selfp, sp);
        (void)hipMemsetAsync(rep2, 0, (size_t)NXCD * NTOT * sizeof(float), stream);
        edge_pass2_x<<<eb, 256, 0, stream>>>(src, dst, sp, rep2, n_edges);
        node2_x<<<NTOT / 256, 256, 0, stream>>>(selfp, rep2, degf, b2, out1, h2t);
        gemm_x<<<dim3(GK / 64, KCHUNKS), 256, 0, stream>>>(h2t, w3, Cpart);
        reduce_x<<<NTOT / 256, 256, 0, stream>>>(Cpart, b3, out2);
    } else {
        // -------- fallback: proven R4 pipeline (4.19 MB) --------
        float* ws = (float*)d_ws;
        float* S0 = ws;            // agg -> selfpart
        float* S1 = ws + 1 * NTOT; // deg
        float* S2 = ws + 2 * NTOT; // agg2
        float* S3 = ws + 3 * NTOT; // sp -> h2t

        (void)hipMemsetAsync(S0, 0, (size_t)3 * NTOT * sizeof(float), stream);
        edge_pass1_f<<<eb, 256, 0, stream>>>(src, dst, nf, S0, S1, n_edges);
        node1_f<<<NTOT / 256, 256, 0, stream>>>(nf, S0, S1, ws1, wn1, b1, ws2, wn2, S3);
        edge_pass2_f<<<eb, 256, 0, stream>>>(src, dst, S3, S2, n_edges);
        node2_f<<<NTOT / 256, 256, 0, stream>>>(S0, S2, S1, b2, b3, out1, S3, out2);
        gemm_f<<<dim3(GK / 256, KCHUNKS), 256, 0, stream>>>(S3, w3, out2);
    }
}

// Round 9
// 405.343 us; speedup vs baseline: 1.3455x; 1.2028x over previous
//
#include <hip/hip_runtime.h>

// GraphPolicyNetwork: 2-layer GraphSAGE (rank-1 weights -> scalar edge passes)
// + dense head [64x4096]@[4096x4096]. All tensors fp32 (proven round 4).
//
// R8 post-mortem: gemm_x at VGPR_Count=36 -- compiler chased occupancy and
// left no registers for h2t loads, so the A-operand became a 4-float-deep
// dependent-load chain (8 cyc FMA per ~200 cyc L2 hit, x4 waves = 16% duty
// == measured VALUBusy 12.6%). Fix: (1) readfirstlane(row0) makes the h2t
// address wave-uniform -> s_load into SGPRs (free FMA operand); (2) explicit
// avA/avB[16] double-buffer + __launch_bounds__(256,2) (VGPR cap 128; grid
// gives 4 waves/SIMD, <=128 VGPR keeps all resident).
// Edge passes: per-XCD replica accumulators (workgroup-scope atomics in the
// local L2, replica = HW_REG_XCC_ID), proven R6.
// Fast path needs 20 MB d_ws; falls back to proven R4 pipeline if smaller.

#define NTOT (64 * 4096)      // 262144 total nodes
#define NHID 128
#define GK   4096             // GEMM K == N_NODES
#define KCH  256              // K per chunk
#define KCHUNKS 16
#define NXCD 8
#define MASK44 ((1ULL << 44) - 1)

typedef unsigned long long u64;

__device__ __forceinline__ int xcc_id() {
    // s_getreg_b32 hwreg(HW_REG_XCC_ID=20, offset 0, size 32): simm16 = 63508.
    return (int)(__builtin_amdgcn_s_getreg(63508) & 7u);
}

__device__ __forceinline__ float fast_tanh(float x) {
    float ax = fabsf(x);
    float t  = __expf(-2.0f * ax);
    float r  = (1.0f - t) / (1.0f + t);
    return copysignf(r, x);
}

// ======================= FAST PATH (ws >= 20 MB) ==========================

// ---- edge pass 1: packed (deg | fixed-point sum) into per-XCD replica ----
__global__ void edge_pass1_x(const int* __restrict__ src, const int* __restrict__ dst,
                             const float* __restrict__ nf, u64* __restrict__ rep,
                             int n_edges) {
    u64* myrep = rep + (size_t)xcc_id() * NTOT;
    int e = blockIdx.x * blockDim.x + threadIdx.x;
    if (e >= n_edges) return;
    float v = nf[src[e]];
    // (v+8) in (2,14); field = (v+8)*2^32; per-replica sum < 64*14*2^32 < 2^42.
    u64 enc = (1ULL << 44) +
              (u64)(long long)llrintf(fmaf(v, 4294967296.0f, 8.0f * 4294967296.0f));
    __hip_atomic_fetch_add(&myrep[dst[e]], enc, __ATOMIC_RELAXED,
                           __HIP_MEMORY_SCOPE_WORKGROUP);
}

// ---- node pass 1: decode replicas; selfpart, sp, deg out ----
__global__ void node1_x(const float* __restrict__ nf, const u64* __restrict__ rep,
                        const float* __restrict__ w_s1, const float* __restrict__ w_n1,
                        const float* __restrict__ bb1,
                        const float* __restrict__ w_s2, const float* __restrict__ w_n2,
                        float* __restrict__ degf, float* __restrict__ selfp,
                        float* __restrict__ sp) {
    __shared__ float lws1[NHID], lwn1[NHID], lb1[NHID], lws2[NHID], lwn2[NHID];
    int tid = threadIdx.x;
    if (tid < NHID) {
        lws1[tid] = w_s1[tid];
        lwn1[tid] = w_n1[tid];
        lb1[tid]  = bb1[tid];
        lws2[tid] = w_s2[tid];
        lwn2[tid] = w_n2[tid];
    }
    __syncthreads();
    int v = blockIdx.x * blockDim.x + tid;
    int degi = 0;
    double sfix = 0.0;
#pragma unroll
    for (int r = 0; r < NXCD; ++r) {
        u64 x = rep[(size_t)r * NTOT + v];
        degi += (int)(x >> 44);
        sfix += (double)(x & MASK44);
    }
    float hsum = (float)(sfix * (1.0 / 4294967296.0) - 8.0 * (double)degi);
    float hn = hsum / fmaxf((float)degi, 1.0f);
    float f = nf[v];
    float a = 0.0f, s = 0.0f;
#pragma unroll 8
    for (int j = 0; j < NHID; ++j) {
        float t = fast_tanh(fmaf(f, lws1[j], fmaf(hn, lwn1[j], lb1[j])));
        a = fmaf(t, lws2[j], a);
        s = fmaf(t, lwn2[j], s);
    }
    degf[v]  = (float)degi;
    selfp[v] = a;
    sp[v]    = s;
}

// ---- edge pass 2: fp32 per-XCD replica accumulation ----
__global__ void edge_pass2_x(const int* __restrict__ src, const int* __restrict__ dst,
                             const float* __restrict__ sp, float* __restrict__ rep2,
                             int n_edges) {
    float* myrep = rep2 + (size_t)xcc_id() * NTOT;
    int e = blockIdx.x * blockDim.x + threadIdx.x;
    if (e >= n_edges) return;
    __hip_atomic_fetch_add(&myrep[dst[e]], sp[src[e]], __ATOMIC_RELAXED,
                           __HIP_MEMORY_SCOPE_WORKGROUP);
}

// ---- node pass 2: out1 (fp32); h2t K-major ----
__global__ void node2_x(const float* __restrict__ selfp, const float* __restrict__ rep2,
                        const float* __restrict__ degf, const float* __restrict__ b2p,
                        float* __restrict__ out1, float* __restrict__ h2t) {
    int v = blockIdx.x * blockDim.x + threadIdx.x;
    float agg2 = 0.0f;
#pragma unroll
    for (int r = 0; r < NXCD; ++r) agg2 += rep2[(size_t)r * NTOT + v];
    float o = selfp[v] + agg2 / fmaxf(degf[v], 1.0f) + b2p[0];
    out1[v] = o;
    int r = v >> 12;     // graph (row) index 0..63
    int k = v & 4095;    // node-in-graph (K) index
    h2t[k * 64 + r] = fast_tanh(o);
}

// ---- GEMM: Cpart[kc][rows][cols]; block tile 64 rows x 64 cols ----
// 4 waves/block, wave w: rows [16w,16w+16); lane = col. acc[16]/thread.
// A-operand (h2t): wave-uniform address via readfirstlane -> s_load
// candidate; explicitly double-buffered (avA/avB, compile-time parity).
// B-operand (w3): 8-deep double-buffered per-lane prefetch (bvA/bvB).
// launch_bounds(256,2): VGPR cap 128; grid 64x16=1024 blocks = 4 waves/SIMD.
__global__ void __launch_bounds__(256, 2) gemm_x(const float* __restrict__ h2t,
                                                 const float* __restrict__ w3,
                                                 float* __restrict__ Cpart) {
    int lane = threadIdx.x & 63;
    int wv   = threadIdx.x >> 6;          // wave 0..3
    int col  = blockIdx.x * 64 + lane;
    int k0   = blockIdx.y * KCH;
    int row0 = __builtin_amdgcn_readfirstlane(wv * 16);   // wave-uniform

    const float* Ap = h2t + (size_t)k0 * 64 + row0;   // A(k) = Ap + k*64 (k in chunk)
    const float* wp = w3 + (size_t)k0 * GK + col;

    float acc[16];
#pragma unroll
    for (int r = 0; r < 16; ++r) acc[r] = 0.0f;

    float bvA[8], bvB[8];      // w3 batches
    float avA[16], avB[16];    // h2t k / k+1

    // prologue
#pragma unroll
    for (int j = 0; j < 8; ++j) bvA[j] = wp[(size_t)j * GK];
#pragma unroll
    for (int r = 0; r < 16; ++r) avA[r] = Ap[r];

    for (int kk = 0; kk < KCH; kk += 16) {
        // issue w3 batch for kk+8..kk+15
#pragma unroll
        for (int j = 0; j < 8; ++j) bvB[j] = wp[(size_t)(kk + 8 + j) * GK];
        // first 8 k's: consume bvA; rotate avA/avB per k (j parity compile-time)
#pragma unroll
        for (int j = 0; j < 8; ++j) {
            const float* An = Ap + (size_t)(kk + j + 1) * 64;
            if ((j & 1) == 0) {
#pragma unroll
                for (int r = 0; r < 16; ++r) avB[r] = An[r];
                float b = bvA[j];
#pragma unroll
                for (int r = 0; r < 16; ++r) acc[r] = fmaf(avA[r], b, acc[r]);
            } else {
#pragma unroll
                for (int r = 0; r < 16; ++r) avA[r] = An[r];
                float b = bvA[j];
#pragma unroll
                for (int r = 0; r < 16; ++r) acc[r] = fmaf(avB[r], b, acc[r]);
            }
        }
        // issue w3 batch for kk+16..kk+23 (uniform guard)
        if (kk + 16 < KCH) {
#pragma unroll
            for (int j = 0; j < 8; ++j) bvA[j] = wp[(size_t)(kk + 16 + j) * GK];
        }
        // second 8 k's: consume bvB; same rotation (parity continues: 8 even)
#pragma unroll
        for (int j = 0; j < 8; ++j) {
            int kn = kk + 8 + j + 1;
            if (kn > KCH - 1) kn = KCH - 1;       // uniform clamp (stay in h2t)
            const float* An = Ap + (size_t)kn * 64;
            if ((j & 1) == 0) {
#pragma unroll
                for (int r = 0; r < 16; ++r) avB[r] = An[r];
                float b = bvB[j];
#pragma unroll
                for (int r = 0; r < 16; ++r) acc[r] = fmaf(avA[r], b, acc[r]);
            } else {
#pragma unroll
                for (int r = 0; r < 16; ++r) avA[r] = An[r];
                float b = bvB[j];
#pragma unroll
                for (int r = 0; r < 16; ++r) acc[r] = fmaf(avB[r], b, acc[r]);
            }
        }
    }

    float* Cp = Cpart + (size_t)blockIdx.y * NTOT + (size_t)row0 * GK + col;
#pragma unroll
    for (int r = 0; r < 16; ++r) Cp[(size_t)r * GK] = acc[r];
}

// ---- reduce K-chunk partials + b3 -> out2 ----
__global__ void reduce_x(const float* __restrict__ Cpart, const float* __restrict__ b3,
                         float* __restrict__ out2) {
    int v = blockIdx.x * blockDim.x + threadIdx.x;
    float s = b3[v & 4095];
#pragma unroll
    for (int kc = 0; kc < KCHUNKS; ++kc) s += Cpart[(size_t)kc * NTOT + v];
    out2[v] = s;
}

// ================== FALLBACK PATH (proven R4 pipeline) ====================

__global__ void edge_pass1_f(const int* __restrict__ src, const int* __restrict__ dst,
                             const float* __restrict__ nf, float* __restrict__ agg,
                             float* __restrict__ deg, int n_edges) {
    int e = blockIdx.x * blockDim.x + threadIdx.x;
    if (e >= n_edges) return;
    int s = src[e], d = dst[e];
    atomicAdd(&agg[d], nf[s]);
    atomicAdd(&deg[d], 1.0f);
}

__global__ void node1_f(const float* __restrict__ nf, float* s0,
                        const float* __restrict__ deg,
                        const float* __restrict__ w_s1, const float* __restrict__ w_n1,
                        const float* __restrict__ bb1,
                        const float* __restrict__ w_s2, const float* __restrict__ w_n2,
                        float* __restrict__ sp) {
    __shared__ float lws1[NHID], lwn1[NHID], lb1[NHID], lws2[NHID], lwn2[NHID];
    int tid = threadIdx.x;
    if (tid < NHID) {
        lws1[tid] = w_s1[tid];
        lwn1[tid] = w_n1[tid];
        lb1[tid]  = bb1[tid];
        lws2[tid] = w_s2[tid];
        lwn2[tid] = w_n2[tid];
    }
    __syncthreads();
    int v = blockIdx.x * blockDim.x + tid;
    float f  = nf[v];
    float hn = s0[v] / fmaxf(deg[v], 1.0f);
    float a = 0.0f, s = 0.0f;
#pragma unroll 8
    for (int j = 0; j < NHID; ++j) {
        float t = fast_tanh(fmaf(f, lws1[j], fmaf(hn, lwn1[j], lb1[j])));
        a = fmaf(t, lws2[j], a);
        s = fmaf(t, lwn2[j], s);
    }
    s0[v] = a;
    sp[v] = s;
}

__global__ void edge_pass2_f(const int* __restrict__ src, const int* __restrict__ dst,
                             const float* __restrict__ sp, float* __restrict__ agg2,
                             int n_edges) {
    int e = blockIdx.x * blockDim.x + threadIdx.x;
    if (e >= n_edges) return;
    atomicAdd(&agg2[dst[e]], sp[src[e]]);
}

__global__ void node2_f(const float* __restrict__ s0, const float* __restrict__ agg2,
                        const float* __restrict__ deg, const float* __restrict__ b2p,
                        const float* __restrict__ b3p,
                        float* __restrict__ out1, float* __restrict__ h2t,
                        float* __restrict__ out2) {
    int v = blockIdx.x * blockDim.x + threadIdx.x;
    float o = s0[v] + agg2[v] / fmaxf(deg[v], 1.0f) + b2p[0];
    out1[v] = o;
    int r = v >> 12;
    int k = v & 4095;
    h2t[k * 64 + r] = fast_tanh(o);
    out2[v] = b3p[v & 4095];
}

__global__ void __launch_bounds__(256) gemm_f(const float* __restrict__ h2t,
                                              const float* __restrict__ w3,
                                              float* __restrict__ out2) {
    int n  = blockIdx.x * 256 + threadIdx.x;
    int k0 = blockIdx.y * KCH;
    float acc[64];
#pragma unroll
    for (int r = 0; r < 64; ++r) acc[r] = 0.0f;
    for (int k = k0; k < k0 + KCH; ++k) {
        float bv = w3[(size_t)k * GK + n];
        const float* Ak = h2t + k * 64;
#pragma unroll
        for (int r = 0; r < 64; ++r) acc[r] = fmaf(Ak[r], bv, acc[r]);
    }
#pragma unroll
    for (int r = 0; r < 64; ++r) atomicAdd(&out2[r * GK + n], acc[r]);
}

// ==========================================================================

extern "C" void kernel_launch(void* const* d_in, const int* in_sizes, int n_in,
                              void* d_out, int out_size, void* d_ws, size_t ws_size,
                              hipStream_t stream) {
    const float* nf  = (const float*)d_in[0];
    const int*   src = (const int*)d_in[1];
    const int*   dst = (const int*)d_in[2];
    const float* ws1 = (const float*)d_in[3];
    const float* wn1 = (const float*)d_in[4];
    const float* b1  = (const float*)d_in[5];
    const float* ws2 = (const float*)d_in[6];
    const float* wn2 = (const float*)d_in[7];
    const float* b2  = (const float*)d_in[8];
    const float* w3  = (const float*)d_in[9];
    const float* b3  = (const float*)d_in[10];
    float* out1 = (float*)d_out;
    float* out2 = (float*)d_out + NTOT;

    int n_edges = in_sizes[1];
    int eb = (n_edges + 255) / 256;

    if (ws_size >= (size_t)20 * 1024 * 1024) {
        // -------- fast path: 20 MB layout --------
        char* base = (char*)d_ws;
        u64*   rep   = (u64*)base;                               // 16 MB
        float* degf  = (float*)(base + (((size_t)16) << 20));    // 1 MB
        float* selfp = (float*)(base + (((size_t)17) << 20));    // 1 MB
        float* sp    = (float*)(base + (((size_t)18) << 20));    // 1 MB
        float* h2t   = (float*)(base + (((size_t)19) << 20));    // 1 MB
        float* rep2  = (float*)base;   // 8 MB, reuses rep after node1
        float* Cpart = (float*)base;   // 16 MB, reuses rep after node2

        (void)hipMemsetAsync(rep, 0, (size_t)NXCD * NTOT * sizeof(u64), stream);
        edge_pass1_x<<<eb, 256, 0, stream>>>(src, dst, nf, rep, n_edges);
        node1_x<<<NTOT / 256, 256, 0, stream>>>(nf, rep, ws1, wn1, b1, ws2, wn2,
                                                degf, selfp, sp);
        (void)hipMemsetAsync(rep2, 0, (size_t)NXCD * NTOT * sizeof(float), stream);
        edge_pass2_x<<<eb, 256, 0, stream>>>(src, dst, sp, rep2, n_edges);
        node2_x<<<NTOT / 256, 256, 0, stream>>>(selfp, rep2, degf, b2, out1, h2t);
        gemm_x<<<dim3(GK / 64, KCHUNKS), 256, 0, stream>>>(h2t, w3, Cpart);
        reduce_x<<<NTOT / 256, 256, 0, stream>>>(Cpart, b3, out2);
    } else {
        // -------- fallback: proven R4 pipeline (4.19 MB) --------
        float* ws = (float*)d_ws;
        float* S0 = ws;            // agg -> selfpart
        float* S1 = ws + 1 * NTOT; // deg
        float* S2 = ws + 2 * NTOT; // agg2
        float* S3 = ws + 3 * NTOT; // sp -> h2t

        (void)hipMemsetAsync(S0, 0, (size_t)3 * NTOT * sizeof(float), stream);
        edge_pass1_f<<<eb, 256, 0, stream>>>(src, dst, nf, S0, S1, n_edges);
        node1_f<<<NTOT / 256, 256, 0, stream>>>(nf, S0, S1, ws1, wn1, b1, ws2, wn2, S3);
        edge_pass2_f<<<eb, 256, 0, stream>>>(src, dst, S3, S2, n_edges);
        node2_f<<<NTOT / 256, 256, 0, stream>>>(S0, S2, S1, b2, b3, out1, S3, out2);
        gemm_f<<<dim3(GK / 256, KCHUNKS), 256, 0, stream>>>(S3, w3, out2);
    }
}